// Round 5
// baseline (2064.309 us; speedup 1.0000x reference)
//
#include <hip/hip_runtime.h>
#include <hip/hip_bf16.h>

typedef __bf16 bf16x8 __attribute__((ext_vector_type(8)));
typedef float f32x4 __attribute__((ext_vector_type(4)));
typedef unsigned short ushort8 __attribute__((ext_vector_type(8)));
typedef float float4v __attribute__((ext_vector_type(4)));
typedef unsigned long long u64;
typedef unsigned int u32;

#define DEVI __device__ __forceinline__

// ---- sizes (compile-time) ----
#define NSEQ 256      // A_*BS
#define TT 256        // T
#define VV 128        // V
#define EE 512        // E
#define HH 512        // H
#define NA 64
#define MROWS 65536   // NSEQ*T
#define G3 1536       // 3*H

DEVI unsigned short f2bf(float f) {
  union { float f; unsigned u; } v; v.f = f;
  unsigned r = v.u + 0x7fffu + ((v.u >> 16) & 1u);
  return (unsigned short)(r >> 16);
}
DEVI float bf2f(unsigned short s) {
  union { unsigned u; float f; } v; v.u = ((unsigned)s) << 16;
  return v.f;
}
DEVI bf16x8 ld_bf8_g(const unsigned short* p) {
  ushort8 v = *(const ushort8*)p;
  return __builtin_bit_cast(bf16x8, v);
}
DEVI bf16x8 ld_bf8_b(const char* base, unsigned byte) {
  ushort8 v = *(const ushort8*)(base + byte);
  return __builtin_bit_cast(bf16x8, v);
}
DEVI void gload_lds16(const void* g, unsigned short* lds_base, unsigned lds_byte_off) {
  __builtin_amdgcn_global_load_lds(
      (const __attribute__((address_space(1))) unsigned int*)g,
      (__attribute__((address_space(3))) unsigned int*)(void*)((char*)lds_base + lds_byte_off),
      16, 0, 0);
}

// ---------- cast fp32 -> bf16(raw u16) ----------
__global__ void cast_f32_bf16(const float* __restrict__ src, unsigned short* __restrict__ dst, int n) {
  int i = blockIdx.x * blockDim.x + threadIdx.x;
  int stride = gridDim.x * blockDim.x;
  for (; i < n; i += stride) dst[i] = f2bf(src[i]);
}

__global__ void zero_u32(u32* __restrict__ p, int n) {
  int i = blockIdx.x * blockDim.x + threadIdx.x;
  if (i < n) p[i] = 0u;
}

// ---------- GEMM: C_bf[M,N] = act(A_bf[M,K] @ W_bf[N,K]^T + bias[N]) ----------
template<bool RELU>
__global__ __launch_bounds__(256)
void gemm_bt(const unsigned short* __restrict__ A, const unsigned short* __restrict__ W,
             const float* __restrict__ bias, unsigned short* __restrict__ C,
             int N, int K) {
  __shared__ unsigned short sA[128 * 64];
  __shared__ unsigned short sB[128 * 64];
  const int tid = threadIdx.x;
  const int w = tid >> 6, lane = tid & 63;
  const int l15 = lane & 15, l4 = lane >> 4;
  const int nbn = N >> 7;
  const int bm = blockIdx.x / nbn, bn = blockIdx.x % nbn;

  f32x4 acc[4][4];
  const f32x4 fz = {0.f, 0.f, 0.f, 0.f};
#pragma unroll
  for (int i = 0; i < 4; i++)
#pragma unroll
    for (int j = 0; j < 4; j++) acc[i][j] = fz;

  const int nk = K >> 6;
  for (int bk = 0; bk < nk; ++bk) {
#pragma unroll
    for (int it = 0; it < 4; ++it) {
      int slot = it * 256 + tid;
      int row = slot >> 3, c16 = slot & 7;
      const unsigned short* ga = A + (size_t)(bm * 128 + row) * K + bk * 64 + c16 * 8;
      const unsigned short* gb = W + (size_t)(bn * 128 + row) * K + bk * 64 + c16 * 8;
      unsigned ldsoff = (unsigned)(it * 256 + w * 64) * 16;
      gload_lds16(ga, sA, ldsoff);
      gload_lds16(gb, sB, ldsoff);
    }
    __syncthreads();
#pragma unroll
    for (int kt = 0; kt < 2; ++kt) {
      bf16x8 af[4], bfr[4];
#pragma unroll
      for (int m = 0; m < 4; m++) {
        int row = ((w >> 1) * 64) + m * 16 + l15;
        af[m] = ld_bf8_g(&sA[row * 64 + kt * 32 + l4 * 8]);
      }
#pragma unroll
      for (int n = 0; n < 4; n++) {
        int row = ((w & 1) * 64) + n * 16 + l15;
        bfr[n] = ld_bf8_g(&sB[row * 64 + kt * 32 + l4 * 8]);
      }
#pragma unroll
      for (int m = 0; m < 4; m++)
#pragma unroll
        for (int n = 0; n < 4; n++)
          acc[m][n] = __builtin_amdgcn_mfma_f32_16x16x32_bf16(af[m], bfr[n], acc[m][n], 0, 0, 0);
    }
    __syncthreads();
  }

  const int r0 = bm * 128 + (w >> 1) * 64;
  const int c0 = bn * 128 + (w & 1) * 64;
#pragma unroll
  for (int n = 0; n < 4; n++) {
    int c = c0 + n * 16 + l15;
    float b = bias[c];
#pragma unroll
    for (int m = 0; m < 4; m++)
#pragma unroll
      for (int j = 0; j < 4; j++) {
        int r = r0 + m * 16 + l4 * 4 + j;
        float v = acc[m][n][j] + b;
        if (RELU) v = fmaxf(v, 0.f);
        C[(size_t)r * N + c] = f2bf(v);
      }
  }
}

// ---------- persistent GRU scan: per-chain counters, wave-independent ----------
// 128 WGs = 8 seq-groups(32 seqs) x 16 col-WGs(32 cols); 256 threads = 4 waves.
// Wave (mm,e): rows mm*16..+16 of group, cols e*16..+16 of WG slice, all gates, full K.
// Chain (sg,mm) = 16 seqs; its 32 producer waves each fetch_add(1) a per-chain
// counter after their exchange stores drain; consumers poll ONE broadcast u32 with
// s_sleep backoff (low LLC traffic — R3's hot 128B spin regressed). Relaxed agent
// atomics only: no buffer_inv/wbl2 anywhere on the serial chain.
#define GRU_LDS_BYTES (96 * 1024)

__global__ __launch_bounds__(256, 1)
void gru_scan(const unsigned short* __restrict__ whh,
              const float* __restrict__ b_hh,
              const unsigned short* __restrict__ gi,
              const float* __restrict__ h0f,
              unsigned short* __restrict__ hbA,   // parity 0 writes
              unsigned short* __restrict__ hbB,   // parity 1 writes (pre-filled f2bf(h0))
              float* __restrict__ hout,
              u32* __restrict__ cnt_base) {       // [16 chains] u32, 128B-spaced, zeroed
  extern __shared__ char lds[];
  unsigned short* sW = (unsigned short*)lds;   // [96][512] bf16, swizzled

  const int tid = threadIdx.x;
  const int w = tid >> 6, lane = tid & 63, l15 = lane & 15, l4 = lane >> 4;
  const int sg = blockIdx.x >> 4, cg = blockIdx.x & 15;
  const int s0 = sg * 32;
  const int c0 = cg * 32;
  const int mm = w >> 1, e = w & 1;

  // ---- one-time: stage whh slice rows (gate*512 + c0 + 0..31) ----
  for (int it = 0; it < 24; ++it) {
    int slot = it * 256 + tid;                 // 6144 slots of 16B
    int lcr = slot >> 6, c16 = slot & 63;      // lcr 0..95
    int grow = (lcr >> 5) * 512 + c0 + (lcr & 31);
    ushort8 v = *(const ushort8*)(whh + (size_t)grow * 512 + c16 * 8);
    unsigned byte = ((unsigned)(lcr * 1024 + c16 * 16)) ^ ((unsigned)(lcr & 7) << 4);
    *(ushort8*)((char*)sW + byte) = v;
  }

  // ---- per-thread constants ----
  const int c = c0 + e * 16 + l15;             // output col
  int rj[4];
#pragma unroll
  for (int j = 0; j < 4; ++j) rj[j] = s0 + mm * 16 + l4 * 4 + j;
  float bias0 = b_hh[c], bias1 = b_hh[512 + c], bias2 = b_hh[1024 + c];
  float hp[4];
#pragma unroll
  for (int j = 0; j < 4; ++j) hp[j] = h0f[(size_t)rj[j] * HH + c];
  size_t houtb[4], gib[4];
#pragma unroll
  for (int j = 0; j < 4; ++j) {
    houtb[j] = (size_t)rj[j] * TT * HH + c;
    gib[j]   = (size_t)rj[j] * TT * G3 + c;
  }
  const int arow = s0 + mm * 16 + l15;         // A-fragment row for this lane
  const unsigned storej = (l15 & 1);           // even lanes store j=0,1; odd j=2,3

  u32* cnt = cnt_base + (sg * 2 + mm) * 32;    // per-chain counter, 128B-spaced

  __syncthreads();  // sW ready (only barrier in the kernel)

#pragma unroll 1
  for (int t = 0; t < TT; ++t) {
    const unsigned short* rb = (t & 1) ? hbA : hbB;
    unsigned short* wb = (t & 1) ? hbB : hbA;

    // prefetch gi(t) — plain cached loads, in flight during the poll
    float gv0[4], gv1[4], gv2[4];
#pragma unroll
    for (int j = 0; j < 4; ++j) {
      const unsigned short* gp = gi + gib[j] + (size_t)t * G3;
      gv0[j] = bf2f(gp[0]);
      gv1[j] = bf2f(gp[512]);
      gv2[j] = bf2f(gp[1024]);
    }

    if (t > 0) {
      // single broadcast-address poll (1 transaction/wave/iter) + short backoff
      u32 target = 32u * (u32)t;
      while (__hip_atomic_load(cnt, __ATOMIC_RELAXED, __HIP_MEMORY_SCOPE_AGENT) < target)
        __builtin_amdgcn_s_sleep(1);
    }

    // ---- A-fragments direct-to-reg: 32 relaxed u64 atomic loads (coherent) ----
    const unsigned short* ap = rb + (size_t)arow * HH + l4 * 8;
    u64 av[32];
#pragma unroll
    for (int ktg = 0; ktg < 16; ++ktg) {
      av[2 * ktg]     = __hip_atomic_load((const u64*)(ap + ktg * 32),
                                          __ATOMIC_RELAXED, __HIP_MEMORY_SCOPE_AGENT);
      av[2 * ktg + 1] = __hip_atomic_load((const u64*)(ap + ktg * 32 + 4),
                                          __ATOMIC_RELAXED, __HIP_MEMORY_SCOPE_AGENT);
    }

    // ---- MFMA: 16 k-steps x 3 gates, full K, no partial reduce ----
    f32x4 acc[3];
    const f32x4 fz = {0.f, 0.f, 0.f, 0.f};
    acc[0] = fz; acc[1] = fz; acc[2] = fz;
#pragma unroll
    for (int ktg = 0; ktg < 16; ++ktg) {
      union { u64 q[2]; bf16x8 v; } ua;
      ua.q[0] = av[2 * ktg]; ua.q[1] = av[2 * ktg + 1];
      bf16x8 a = ua.v;
#pragma unroll
      for (int g = 0; g < 3; ++g) {
        int lcr = g * 32 + e * 16 + l15;
        unsigned byte = ((unsigned)(lcr * 1024 + ktg * 64 + l4 * 16)) ^ ((unsigned)(lcr & 7) << 4);
        bf16x8 b = ld_bf8_b((const char*)sW, byte);
        acc[g] = __builtin_amdgcn_mfma_f32_16x16x32_bf16(a, b, acc[g], 0, 0, 0);
      }
    }

    // ---- epilogue: each thread owns r,z,n for 4 (row, col=c) outputs ----
    float hn[4];
#pragma unroll
    for (int j = 0; j < 4; ++j) {
      float gh0 = acc[0][j] + bias0;
      float gh1 = acc[1][j] + bias1;
      float gh2 = acc[2][j] + bias2;
      float rr = 1.f / (1.f + __expf(-(gv0[j] + gh0)));
      float zz = 1.f / (1.f + __expf(-(gv1[j] + gh1)));
      float nx = gv2[j] + rr * gh2;
      float ex = __expf(2.f * nx);
      float nn = 1.f - 2.f / (ex + 1.f);       // tanh, inf-safe
      hn[j] = (1.f - zz) * nn + zz * hp[j];
      hp[j] = hn[j];
    }

    // ---- exchange first (critical path): pack col-pairs, relaxed u32 stores ----
#pragma unroll
    for (int j = 0; j < 4; ++j) {
      u32 my = f2bf(hn[j]);
      u32 oth = (u32)__shfl_xor((int)my, 1);
      u32 word = (l15 & 1) ? ((oth & 0xffffu) | (my << 16))
                           : ((my & 0xffffu) | (oth << 16));
      if ((unsigned)(j >> 1) == storej) {
        u32* dst = (u32*)(wb + (size_t)rj[j] * HH + (c & ~1));
        __hip_atomic_store(dst, word, __ATOMIC_RELAXED, __HIP_MEMORY_SCOPE_AGENT);
      }
    }

    // drain: exchange stores ACKed at the coherence point, then publish
    asm volatile("s_waitcnt vmcnt(0)" ::: "memory");
    if (lane == 0)
      __hip_atomic_fetch_add(cnt, 1u, __ATOMIC_RELAXED, __HIP_MEMORY_SCOPE_AGENT);

    // hout off the critical path (plain cached stores, flushed at kernel end)
#pragma unroll
    for (int j = 0; j < 4; ++j)
      hout[houtb[j] + (size_t)t * HH] = hn[j];
  }
}

// ---------- decoder + softmax ----------
__global__ __launch_bounds__(256)
void decoder_softmax(const float* __restrict__ hf,
                     const unsigned short* __restrict__ dwb,
                     const float* __restrict__ dec_b,
                     float* __restrict__ pi) {
  __shared__ unsigned short sH[64 * 512];
  const int tid = threadIdx.x, w = tid >> 6, lane = tid & 63, l15 = lane & 15, l4 = lane >> 4;
  const size_t m0 = (size_t)blockIdx.x * 64;

#pragma unroll
  for (int it = 0; it < 16; ++it) {
    int slot = it * 256 + tid;
    int row = slot >> 6, c16 = slot & 63;
    const float* g = hf + (m0 + row) * 512 + c16 * 8;
    float4v v0 = *(const float4v*)g;
    float4v v1 = *(const float4v*)(g + 4);
    ushort8 u;
    u[0] = f2bf(v0[0]); u[1] = f2bf(v0[1]); u[2] = f2bf(v0[2]); u[3] = f2bf(v0[3]);
    u[4] = f2bf(v1[0]); u[5] = f2bf(v1[1]); u[6] = f2bf(v1[2]); u[7] = f2bf(v1[3]);
    unsigned byte = ((unsigned)(row * 1024 + c16 * 16)) ^ ((unsigned)(row & 7) << 4);
    *(ushort8*)((char*)sH + byte) = u;
  }
  __syncthreads();

  f32x4 acc[4];
  const f32x4 fz = {0.f, 0.f, 0.f, 0.f};
#pragma unroll
  for (int n = 0; n < 4; n++) acc[n] = fz;

  for (int kt = 0; kt < 16; ++kt) {
    int row = w * 16 + l15;
    unsigned byte = ((unsigned)(row * 1024 + kt * 64 + l4 * 16)) ^ ((unsigned)(row & 7) << 4);
    bf16x8 a = ld_bf8_b((const char*)sH, byte);
#pragma unroll
    for (int nt = 0; nt < 4; nt++) {
      bf16x8 b = ld_bf8_g(dwb + (size_t)(nt * 16 + l15) * 512 + kt * 32 + l4 * 8);
      acc[nt] = __builtin_amdgcn_mfma_f32_16x16x32_bf16(a, b, acc[nt], 0, 0, 0);
    }
  }

#pragma unroll
  for (int j = 0; j < 4; j++) {
    size_t r = m0 + w * 16 + l4 * 4 + j;
    float v[4];
    float mx = -1e30f;
#pragma unroll
    for (int nt = 0; nt < 4; nt++) {
      v[nt] = fmaxf(acc[nt][j] + dec_b[nt * 16 + l15], 0.f);
      mx = fmaxf(mx, v[nt]);
    }
#pragma unroll
    for (int msk = 1; msk <= 8; msk <<= 1) mx = fmaxf(mx, __shfl_xor(mx, msk));
    float s = 0.f;
#pragma unroll
    for (int nt = 0; nt < 4; nt++) { v[nt] = __expf(v[nt] - mx); s += v[nt]; }
#pragma unroll
    for (int msk = 1; msk <= 8; msk <<= 1) s += __shfl_xor(s, msk);
    float inv = 1.f / s;
#pragma unroll
    for (int nt = 0; nt < 4; nt++) pi[r * 64 + nt * 16 + l15] = v[nt] * inv;
  }
}

extern "C" void kernel_launch(void* const* d_in, const int* in_sizes, int n_in,
                              void* d_out, int out_size, void* d_ws, size_t ws_size,
                              hipStream_t stream) {
  const float* x     = (const float*)d_in[0];
  const float* h0    = (const float*)d_in[1];
  const float* enc_w = (const float*)d_in[2];
  const float* enc_b = (const float*)d_in[3];
  const float* w_ih  = (const float*)d_in[4];
  const float* w_hh  = (const float*)d_in[5];
  const float* b_ih  = (const float*)d_in[6];
  const float* b_hh  = (const float*)d_in[7];
  const float* dec_w = (const float*)d_in[8];
  const float* dec_b = (const float*)d_in[9];

  float* pi_out = (float*)d_out;
  float* h_out  = (float*)d_out + 4194304;

  unsigned short* ws = (unsigned short*)d_ws;
  size_t off = 0;
  unsigned short* x_bf    = ws + off; off += (size_t)MROWS * VV;
  unsigned short* enc_bf  = ws + off; off += (size_t)MROWS * EE;
  unsigned short* gi_bf   = ws + off; off += (size_t)MROWS * G3;
  unsigned short* encw_bf = ws + off; off += (size_t)EE * VV;
  unsigned short* wih_bf  = ws + off; off += (size_t)G3 * EE;
  unsigned short* whh_bf  = ws + off; off += (size_t)G3 * HH;
  unsigned short* decw_bf = ws + off; off += (size_t)NA * HH;
  unsigned short* hb0     = ws + off; off += (size_t)NSEQ * HH;
  unsigned short* hb1     = ws + off; off += (size_t)NSEQ * HH;
  u32*            cnt32   = (u32*)(ws + off); off += 2048;   // 1024 u32
  (void)ws_size; (void)in_sizes; (void)n_in; (void)out_size;

  hipFuncSetAttribute((const void*)gru_scan,
                      hipFuncAttributeMaxDynamicSharedMemorySize, GRU_LDS_BYTES);

  auto cast = [&](const float* s, unsigned short* d, int n) {
    int blocks = (n + 255) / 256; if (blocks > 2048) blocks = 2048;
    cast_f32_bf16<<<blocks, 256, 0, stream>>>(s, d, n);
  };
  cast(x, x_bf, MROWS * VV);
  cast(enc_w, encw_bf, EE * VV);
  cast(w_ih, wih_bf, G3 * EE);
  cast(w_hh, whh_bf, G3 * HH);
  cast(dec_w, decw_bf, NA * HH);
  cast(h0, hb1, NSEQ * HH);              // t=0 reads hbB == hb1

  zero_u32<<<4, 256, 0, stream>>>(cnt32, 1024);

  gemm_bt<true><<<(MROWS / 128) * (EE / 128), 256, 0, stream>>>(x_bf, encw_bf, enc_b, enc_bf, EE, VV);
  gemm_bt<false><<<(MROWS / 128) * (G3 / 128), 256, 0, stream>>>(enc_bf, wih_bf, b_ih, gi_bf, G3, EE);

  gru_scan<<<dim3(128), dim3(256), GRU_LDS_BYTES, stream>>>(
      whh_bf, b_hh, gi_bf, h0, hb0, hb1, h_out, cnt32);

  decoder_softmax<<<1024, 256, 0, stream>>>(h_out, decw_bf, dec_b, pi_out);
}

// Round 7
// 2057.892 us; speedup vs baseline: 1.0031x; 1.0031x over previous
//
#include <hip/hip_runtime.h>
#include <hip/hip_bf16.h>

typedef __bf16 bf16x8 __attribute__((ext_vector_type(8)));
typedef float f32x4 __attribute__((ext_vector_type(4)));
typedef unsigned short ushort8 __attribute__((ext_vector_type(8)));
typedef float float4v __attribute__((ext_vector_type(4)));
typedef unsigned long long u64;
typedef unsigned int u32;

#define DEVI __device__ __forceinline__

// ---- sizes (compile-time) ----
#define NSEQ 256      // A_*BS
#define TT 256        // T
#define VV 128        // V
#define EE 512        // E
#define HH 512        // H
#define NA 64
#define MROWS 65536   // NSEQ*T
#define G3 1536       // 3*H

DEVI unsigned short f2bf(float f) {
  union { float f; unsigned u; } v; v.f = f;
  unsigned r = v.u + 0x7fffu + ((v.u >> 16) & 1u);
  return (unsigned short)(r >> 16);
}
DEVI float bf2f(unsigned short s) {
  union { unsigned u; float f; } v; v.u = ((unsigned)s) << 16;
  return v.f;
}
DEVI bf16x8 ld_bf8_g(const unsigned short* p) {
  ushort8 v = *(const ushort8*)p;
  return __builtin_bit_cast(bf16x8, v);
}
DEVI bf16x8 ld_bf8_b(const char* base, unsigned byte) {
  ushort8 v = *(const ushort8*)(base + byte);
  return __builtin_bit_cast(bf16x8, v);
}
DEVI void gload_lds16(const void* g, unsigned short* lds_base, unsigned lds_byte_off) {
  __builtin_amdgcn_global_load_lds(
      (const __attribute__((address_space(1))) unsigned int*)g,
      (__attribute__((address_space(3))) unsigned int*)(void*)((char*)lds_base + lds_byte_off),
      16, 0, 0);
}

// ---------- cast fp32 -> bf16(raw u16) ----------
__global__ void cast_f32_bf16(const float* __restrict__ src, unsigned short* __restrict__ dst, int n) {
  int i = blockIdx.x * blockDim.x + threadIdx.x;
  int stride = gridDim.x * blockDim.x;
  for (; i < n; i += stride) dst[i] = f2bf(src[i]);
}

__global__ void zero_u32(u32* __restrict__ p, int n) {
  int i = blockIdx.x * blockDim.x + threadIdx.x;
  if (i < n) p[i] = 0u;
}

// ---------- GEMM: C_bf[M,N] = act(A_bf[M,K] @ W_bf[N,K]^T + bias[N]) ----------
template<bool RELU>
__global__ __launch_bounds__(256)
void gemm_bt(const unsigned short* __restrict__ A, const unsigned short* __restrict__ W,
             const float* __restrict__ bias, unsigned short* __restrict__ C,
             int N, int K) {
  __shared__ unsigned short sA[128 * 64];
  __shared__ unsigned short sB[128 * 64];
  const int tid = threadIdx.x;
  const int w = tid >> 6, lane = tid & 63;
  const int l15 = lane & 15, l4 = lane >> 4;
  const int nbn = N >> 7;
  const int bm = blockIdx.x / nbn, bn = blockIdx.x % nbn;

  f32x4 acc[4][4];
  const f32x4 fz = {0.f, 0.f, 0.f, 0.f};
#pragma unroll
  for (int i = 0; i < 4; i++)
#pragma unroll
    for (int j = 0; j < 4; j++) acc[i][j] = fz;

  const int nk = K >> 6;
  for (int bk = 0; bk < nk; ++bk) {
#pragma unroll
    for (int it = 0; it < 4; ++it) {
      int slot = it * 256 + tid;
      int row = slot >> 3, c16 = slot & 7;
      const unsigned short* ga = A + (size_t)(bm * 128 + row) * K + bk * 64 + c16 * 8;
      const unsigned short* gb = W + (size_t)(bn * 128 + row) * K + bk * 64 + c16 * 8;
      unsigned ldsoff = (unsigned)(it * 256 + w * 64) * 16;
      gload_lds16(ga, sA, ldsoff);
      gload_lds16(gb, sB, ldsoff);
    }
    __syncthreads();
#pragma unroll
    for (int kt = 0; kt < 2; ++kt) {
      bf16x8 af[4], bfr[4];
#pragma unroll
      for (int m = 0; m < 4; m++) {
        int row = ((w >> 1) * 64) + m * 16 + l15;
        af[m] = ld_bf8_g(&sA[row * 64 + kt * 32 + l4 * 8]);
      }
#pragma unroll
      for (int n = 0; n < 4; n++) {
        int row = ((w & 1) * 64) + n * 16 + l15;
        bfr[n] = ld_bf8_g(&sB[row * 64 + kt * 32 + l4 * 8]);
      }
#pragma unroll
      for (int m = 0; m < 4; m++)
#pragma unroll
        for (int n = 0; n < 4; n++)
          acc[m][n] = __builtin_amdgcn_mfma_f32_16x16x32_bf16(af[m], bfr[n], acc[m][n], 0, 0, 0);
    }
    __syncthreads();
  }

  const int r0 = bm * 128 + (w >> 1) * 64;
  const int c0 = bn * 128 + (w & 1) * 64;
#pragma unroll
  for (int n = 0; n < 4; n++) {
    int c = c0 + n * 16 + l15;
    float b = bias[c];
#pragma unroll
    for (int m = 0; m < 4; m++)
#pragma unroll
      for (int j = 0; j < 4; j++) {
        int r = r0 + m * 16 + l4 * 4 + j;
        float v = acc[m][n][j] + b;
        if (RELU) v = fmaxf(v, 0.f);
        C[(size_t)r * N + c] = f2bf(v);
      }
  }
}

// ---------- persistent GRU scan ----------
// 128 WGs = 8 seq-groups(32 seqs) x 16 col-WGs(32 cols); 256 threads = 4 waves.
// Wave (mm,e): rows mm*16..+16, cols e*16..+16, all 3 gates, full K=512.
// PUBLISH (per wave, correct by construction — R3-proven): exchange stores ->
//   explicit s_waitcnt vmcnt(0) (agent-relaxed stores ACKed at LLC) -> lane0
//   plain relaxed store of this wave's flag. No RMW, no barrier-dependence
//   (R5's tid0-after-__syncthreads publish RACED: barrier does not imply
//   other waves' agent-scope stores reached the LLC).
// DETECT (cheap — R5-style): wave 0 polls all 64 same-sg per-wave flags with one
//   coalesced 256B load + 6-step shfl-min + s_sleep backoff; __syncthreads releases.
#define GRU_LDS_BYTES (96 * 1024)

__global__ __launch_bounds__(256, 1)
void gru_scan(const unsigned short* __restrict__ whh,
              const float* __restrict__ b_hh,
              const unsigned short* __restrict__ gi,
              const float* __restrict__ h0f,
              unsigned short* __restrict__ hbA,   // parity 0 writes
              unsigned short* __restrict__ hbB,   // parity 1 writes (pre-filled f2bf(h0))
              float* __restrict__ hout,
              u32* __restrict__ flags) {          // [8 sg][64 waves] u32, zeroed
  extern __shared__ char lds[];
  unsigned short* sW = (unsigned short*)lds;   // [96][512] bf16, swizzled

  const int tid = threadIdx.x;
  const int w = tid >> 6, lane = tid & 63, l15 = lane & 15, l4 = lane >> 4;
  const int sg = blockIdx.x >> 4, cg = blockIdx.x & 15;
  const int s0 = sg * 32;
  const int c0 = cg * 32;
  const int mm = w >> 1, e = w & 1;

  // ---- one-time: stage whh slice rows (gate*512 + c0 + 0..31) ----
  for (int it = 0; it < 24; ++it) {
    int slot = it * 256 + tid;                 // 6144 slots of 16B
    int lcr = slot >> 6, c16 = slot & 63;      // lcr 0..95
    int grow = (lcr >> 5) * 512 + c0 + (lcr & 31);
    ushort8 v = *(const ushort8*)(whh + (size_t)grow * 512 + c16 * 8);
    unsigned byte = ((unsigned)(lcr * 1024 + c16 * 16)) ^ ((unsigned)(lcr & 7) << 4);
    *(ushort8*)((char*)sW + byte) = v;
  }

  // ---- per-thread constants ----
  const int c = c0 + e * 16 + l15;             // output col
  int rj[4];
#pragma unroll
  for (int j = 0; j < 4; ++j) rj[j] = s0 + mm * 16 + l4 * 4 + j;
  float bias0 = b_hh[c], bias1 = b_hh[512 + c], bias2 = b_hh[1024 + c];
  float hp[4];
#pragma unroll
  for (int j = 0; j < 4; ++j) hp[j] = h0f[(size_t)rj[j] * HH + c];
  size_t houtb[4], gib[4];
#pragma unroll
  for (int j = 0; j < 4; ++j) {
    houtb[j] = (size_t)rj[j] * TT * HH + c;
    gib[j]   = (size_t)rj[j] * TT * G3 + c;
  }
  const int arow = s0 + mm * 16 + l15;         // A-fragment row for this lane
  const unsigned storej = (l15 & 1);           // even lanes store j=0,1; odd j=2,3

  u32* myflag = flags + sg * 64 + cg * 4 + w;  // per-WAVE flag
  const u32* pollp = flags + sg * 64 + lane;   // wave0: all 64 same-sg flags

  __syncthreads();  // sW ready

#pragma unroll 1
  for (int t = 0; t < TT; ++t) {
    const unsigned short* rb = (t & 1) ? hbA : hbB;
    unsigned short* wb = (t & 1) ? hbB : hbA;

    // prefetch gi(t) — plain cached loads, in flight during the poll
    float gv0[4], gv1[4], gv2[4];
#pragma unroll
    for (int j = 0; j < 4; ++j) {
      const unsigned short* gp = gi + gib[j] + (size_t)t * G3;
      gv0[j] = bf2f(gp[0]);
      gv1[j] = bf2f(gp[512]);
      gv2[j] = bf2f(gp[1024]);
    }

    if (t > 0) {
      if (w == 0) {
        // one coalesced 256B load of all 64 per-wave flags + full-wave min
        int mv;
        do {
          u32 v = __hip_atomic_load(pollp, __ATOMIC_RELAXED, __HIP_MEMORY_SCOPE_AGENT);
          mv = (int)v;
#pragma unroll
          for (int msk = 1; msk <= 32; msk <<= 1) {
            int o = __shfl_xor(mv, msk);
            mv = mv < o ? mv : o;
          }
          if (mv < t) __builtin_amdgcn_s_sleep(1);
        } while (mv < t);
      }
      __syncthreads();   // release WG: h_{t-1} known complete at LLC
    }

    // ---- A-fragments direct-to-reg: 32 relaxed u64 atomic loads (coherent) ----
    const unsigned short* ap = rb + (size_t)arow * HH + l4 * 8;
    u64 av[32];
#pragma unroll
    for (int ktg = 0; ktg < 16; ++ktg) {
      av[2 * ktg]     = __hip_atomic_load((const u64*)(ap + ktg * 32),
                                          __ATOMIC_RELAXED, __HIP_MEMORY_SCOPE_AGENT);
      av[2 * ktg + 1] = __hip_atomic_load((const u64*)(ap + ktg * 32 + 4),
                                          __ATOMIC_RELAXED, __HIP_MEMORY_SCOPE_AGENT);
    }

    // ---- MFMA: 16 k-steps x 3 gates, full K, no partial reduce ----
    f32x4 acc[3];
    const f32x4 fz = {0.f, 0.f, 0.f, 0.f};
    acc[0] = fz; acc[1] = fz; acc[2] = fz;
#pragma unroll
    for (int ktg = 0; ktg < 16; ++ktg) {
      union { u64 q[2]; bf16x8 v; } ua;
      ua.q[0] = av[2 * ktg]; ua.q[1] = av[2 * ktg + 1];
      bf16x8 a = ua.v;
#pragma unroll
      for (int g = 0; g < 3; ++g) {
        int lcr = g * 32 + e * 16 + l15;
        unsigned byte = ((unsigned)(lcr * 1024 + ktg * 64 + l4 * 16)) ^ ((unsigned)(lcr & 7) << 4);
        bf16x8 b = ld_bf8_b((const char*)sW, byte);
        acc[g] = __builtin_amdgcn_mfma_f32_16x16x32_bf16(a, b, acc[g], 0, 0, 0);
      }
    }

    // ---- epilogue: each thread owns r,z,n for 4 (row, col=c) outputs ----
    float hn[4];
#pragma unroll
    for (int j = 0; j < 4; ++j) {
      float gh0 = acc[0][j] + bias0;
      float gh1 = acc[1][j] + bias1;
      float gh2 = acc[2][j] + bias2;
      float rr = 1.f / (1.f + __expf(-(gv0[j] + gh0)));
      float zz = 1.f / (1.f + __expf(-(gv1[j] + gh1)));
      float nx = gv2[j] + rr * gh2;
      float ex = __expf(2.f * nx);
      float nn = 1.f - 2.f / (ex + 1.f);       // tanh, inf-safe
      hn[j] = (1.f - zz) * nn + zz * hp[j];
      hp[j] = hn[j];
      hout[houtb[j] + (size_t)t * HH] = hn[j]; // plain cached store, drained below
    }

    // ---- exchange: pack col-pairs via shfl, relaxed u32 atomic stores ----
#pragma unroll
    for (int j = 0; j < 4; ++j) {
      u32 my = f2bf(hn[j]);
      u32 oth = (u32)__shfl_xor((int)my, 1);
      u32 word = (l15 & 1) ? ((oth & 0xffffu) | (my << 16))
                           : ((my & 0xffffu) | (oth << 16));
      if ((unsigned)(j >> 1) == storej) {
        u32* dst = (u32*)(wb + (size_t)rj[j] * HH + (c & ~1));
        __hip_atomic_store(dst, word, __ATOMIC_RELAXED, __HIP_MEMORY_SCOPE_AGENT);
      }
    }

    // per-wave publish: this wave's stores ACKed at LLC, then its own flag
    asm volatile("s_waitcnt vmcnt(0)" ::: "memory");
    if (lane == 0)
      __hip_atomic_store(myflag, (u32)(t + 1), __ATOMIC_RELAXED, __HIP_MEMORY_SCOPE_AGENT);
  }
}

// ---------- decoder + softmax ----------
__global__ __launch_bounds__(256)
void decoder_softmax(const float* __restrict__ hf,
                     const unsigned short* __restrict__ dwb,
                     const float* __restrict__ dec_b,
                     float* __restrict__ pi) {
  __shared__ unsigned short sH[64 * 512];
  const int tid = threadIdx.x, w = tid >> 6, lane = tid & 63, l15 = lane & 15, l4 = lane >> 4;
  const size_t m0 = (size_t)blockIdx.x * 64;

#pragma unroll
  for (int it = 0; it < 16; ++it) {
    int slot = it * 256 + tid;
    int row = slot >> 6, c16 = slot & 63;
    const float* g = hf + (m0 + row) * 512 + c16 * 8;
    float4v v0 = *(const float4v*)g;
    float4v v1 = *(const float4v*)(g + 4);
    ushort8 u;
    u[0] = f2bf(v0[0]); u[1] = f2bf(v0[1]); u[2] = f2bf(v0[2]); u[3] = f2bf(v0[3]);
    u[4] = f2bf(v1[0]); u[5] = f2bf(v1[1]); u[6] = f2bf(v1[2]); u[7] = f2bf(v1[3]);
    unsigned byte = ((unsigned)(row * 1024 + c16 * 16)) ^ ((unsigned)(row & 7) << 4);
    *(ushort8*)((char*)sH + byte) = u;
  }
  __syncthreads();

  f32x4 acc[4];
  const f32x4 fz = {0.f, 0.f, 0.f, 0.f};
#pragma unroll
  for (int n = 0; n < 4; n++) acc[n] = fz;

  for (int kt = 0; kt < 16; ++kt) {
    int row = w * 16 + l15;
    unsigned byte = ((unsigned)(row * 1024 + kt * 64 + l4 * 16)) ^ ((unsigned)(row & 7) << 4);
    bf16x8 a = ld_bf8_b((const char*)sH, byte);
#pragma unroll
    for (int nt = 0; nt < 4; nt++) {
      bf16x8 b = ld_bf8_g(dwb + (size_t)(nt * 16 + l15) * 512 + kt * 32 + l4 * 8);
      acc[nt] = __builtin_amdgcn_mfma_f32_16x16x32_bf16(a, b, acc[nt], 0, 0, 0);
    }
  }

#pragma unroll
  for (int j = 0; j < 4; j++) {
    size_t r = m0 + w * 16 + l4 * 4 + j;
    float v[4];
    float mx = -1e30f;
#pragma unroll
    for (int nt = 0; nt < 4; nt++) {
      v[nt] = fmaxf(acc[nt][j] + dec_b[nt * 16 + l15], 0.f);
      mx = fmaxf(mx, v[nt]);
    }
#pragma unroll
    for (int msk = 1; msk <= 8; msk <<= 1) mx = fmaxf(mx, __shfl_xor(mx, msk));
    float s = 0.f;
#pragma unroll
    for (int nt = 0; nt < 4; nt++) { v[nt] = __expf(v[nt] - mx); s += v[nt]; }
#pragma unroll
    for (int msk = 1; msk <= 8; msk <<= 1) s += __shfl_xor(s, msk);
    float inv = 1.f / s;
#pragma unroll
    for (int nt = 0; nt < 4; nt++) pi[r * 64 + nt * 16 + l15] = v[nt] * inv;
  }
}

extern "C" void kernel_launch(void* const* d_in, const int* in_sizes, int n_in,
                              void* d_out, int out_size, void* d_ws, size_t ws_size,
                              hipStream_t stream) {
  const float* x     = (const float*)d_in[0];
  const float* h0    = (const float*)d_in[1];
  const float* enc_w = (const float*)d_in[2];
  const float* enc_b = (const float*)d_in[3];
  const float* w_ih  = (const float*)d_in[4];
  const float* w_hh  = (const float*)d_in[5];
  const float* b_ih  = (const float*)d_in[6];
  const float* b_hh  = (const float*)d_in[7];
  const float* dec_w = (const float*)d_in[8];
  const float* dec_b = (const float*)d_in[9];

  float* pi_out = (float*)d_out;
  float* h_out  = (float*)d_out + 4194304;

  unsigned short* ws = (unsigned short*)d_ws;
  size_t off = 0;
  unsigned short* x_bf    = ws + off; off += (size_t)MROWS * VV;
  unsigned short* enc_bf  = ws + off; off += (size_t)MROWS * EE;
  unsigned short* gi_bf   = ws + off; off += (size_t)MROWS * G3;
  unsigned short* encw_bf = ws + off; off += (size_t)EE * VV;
  unsigned short* wih_bf  = ws + off; off += (size_t)G3 * EE;
  unsigned short* whh_bf  = ws + off; off += (size_t)G3 * HH;
  unsigned short* decw_bf = ws + off; off += (size_t)NA * HH;
  unsigned short* hb0     = ws + off; off += (size_t)NSEQ * HH;
  unsigned short* hb1     = ws + off; off += (size_t)NSEQ * HH;
  u32* flags = (u32*)((((uintptr_t)(ws + off)) + 255) & ~(uintptr_t)255);
  (void)ws_size; (void)in_sizes; (void)n_in; (void)out_size;

  hipFuncSetAttribute((const void*)gru_scan,
                      hipFuncAttributeMaxDynamicSharedMemorySize, GRU_LDS_BYTES);

  auto cast = [&](const float* s, unsigned short* d, int n) {
    int blocks = (n + 255) / 256; if (blocks > 2048) blocks = 2048;
    cast_f32_bf16<<<blocks, 256, 0, stream>>>(s, d, n);
  };
  cast(x, x_bf, MROWS * VV);
  cast(enc_w, encw_bf, EE * VV);
  cast(w_ih, wih_bf, G3 * EE);
  cast(w_hh, whh_bf, G3 * HH);
  cast(dec_w, decw_bf, NA * HH);
  cast(h0, hb1, NSEQ * HH);              // t=0 reads hbB == hb1

  zero_u32<<<2, 256, 0, stream>>>(flags, 512);

  gemm_bt<true><<<(MROWS / 128) * (EE / 128), 256, 0, stream>>>(x_bf, encw_bf, enc_b, enc_bf, EE, VV);
  gemm_bt<false><<<(MROWS / 128) * (G3 / 128), 256, 0, stream>>>(enc_bf, wih_bf, b_ih, gi_bf, G3, EE);

  gru_scan<<<dim3(128), dim3(256), GRU_LDS_BYTES, stream>>>(
      whh_bf, b_hh, gi_bf, h0, hb0, hb1, h_out, flags);

  decoder_softmax<<<1024, 256, 0, stream>>>(h_out, decw_bf, dec_b, pi_out);
}

// Round 9
// 1829.398 us; speedup vs baseline: 1.1284x; 1.1249x over previous
//
#include <hip/hip_runtime.h>
#include <hip/hip_bf16.h>

typedef __bf16 bf16x8 __attribute__((ext_vector_type(8)));
typedef float f32x4 __attribute__((ext_vector_type(4)));
typedef unsigned short ushort8 __attribute__((ext_vector_type(8)));
typedef float float4v __attribute__((ext_vector_type(4)));
typedef unsigned long long u64;
typedef unsigned int u32;

#define DEVI __device__ __forceinline__

// ---- sizes (compile-time) ----
#define NSEQ 256      // A_*BS
#define TT 256        // T
#define VV 128        // V
#define EE 512        // E
#define HH 512        // H
#define NA 64
#define MROWS 65536   // NSEQ*T
#define G3 1536       // 3*H

DEVI unsigned short f2bf(float f) {
  union { float f; unsigned u; } v; v.f = f;
  unsigned r = v.u + 0x7fffu + ((v.u >> 16) & 1u);
  return (unsigned short)(r >> 16);
}
DEVI float bf2f(unsigned short s) {
  union { unsigned u; float f; } v; v.u = ((unsigned)s) << 16;
  return v.f;
}
DEVI bf16x8 ld_bf8_g(const unsigned short* p) {
  ushort8 v = *(const ushort8*)p;
  return __builtin_bit_cast(bf16x8, v);
}
DEVI bf16x8 ld_bf8_b(const char* base, unsigned byte) {
  ushort8 v = *(const ushort8*)(base + byte);
  return __builtin_bit_cast(bf16x8, v);
}
DEVI void gload_lds16(const void* g, unsigned short* lds_base, unsigned lds_byte_off) {
  __builtin_amdgcn_global_load_lds(
      (const __attribute__((address_space(1))) unsigned int*)g,
      (__attribute__((address_space(3))) unsigned int*)(void*)((char*)lds_base + lds_byte_off),
      16, 0, 0);
}

// ---------- cast fp32 -> bf16(raw u16) ----------
__global__ void cast_f32_bf16(const float* __restrict__ src, unsigned short* __restrict__ dst, int n) {
  int i = blockIdx.x * blockDim.x + threadIdx.x;
  int stride = gridDim.x * blockDim.x;
  for (; i < n; i += stride) dst[i] = f2bf(src[i]);
}

__global__ void zero_u32(u32* __restrict__ p, int n) {
  int i = blockIdx.x * blockDim.x + threadIdx.x;
  if (i < n) p[i] = 0u;
}

// ---------- GEMM: C_bf[M,N] = act(A_bf[M,K] @ W_bf[N,K]^T + bias[N]) ----------
template<bool RELU>
__global__ __launch_bounds__(256)
void gemm_bt(const unsigned short* __restrict__ A, const unsigned short* __restrict__ W,
             const float* __restrict__ bias, unsigned short* __restrict__ C,
             int N, int K) {
  __shared__ unsigned short sA[128 * 64];
  __shared__ unsigned short sB[128 * 64];
  const int tid = threadIdx.x;
  const int w = tid >> 6, lane = tid & 63;
  const int l15 = lane & 15, l4 = lane >> 4;
  const int nbn = N >> 7;
  const int bm = blockIdx.x / nbn, bn = blockIdx.x % nbn;

  f32x4 acc[4][4];
  const f32x4 fz = {0.f, 0.f, 0.f, 0.f};
#pragma unroll
  for (int i = 0; i < 4; i++)
#pragma unroll
    for (int j = 0; j < 4; j++) acc[i][j] = fz;

  const int nk = K >> 6;
  for (int bk = 0; bk < nk; ++bk) {
#pragma unroll
    for (int it = 0; it < 4; ++it) {
      int slot = it * 256 + tid;
      int row = slot >> 3, c16 = slot & 7;
      const unsigned short* ga = A + (size_t)(bm * 128 + row) * K + bk * 64 + c16 * 8;
      const unsigned short* gb = W + (size_t)(bn * 128 + row) * K + bk * 64 + c16 * 8;
      unsigned ldsoff = (unsigned)(it * 256 + w * 64) * 16;
      gload_lds16(ga, sA, ldsoff);
      gload_lds16(gb, sB, ldsoff);
    }
    __syncthreads();
#pragma unroll
    for (int kt = 0; kt < 2; ++kt) {
      bf16x8 af[4], bfr[4];
#pragma unroll
      for (int m = 0; m < 4; m++) {
        int row = ((w >> 1) * 64) + m * 16 + l15;
        af[m] = ld_bf8_g(&sA[row * 64 + kt * 32 + l4 * 8]);
      }
#pragma unroll
      for (int n = 0; n < 4; n++) {
        int row = ((w & 1) * 64) + n * 16 + l15;
        bfr[n] = ld_bf8_g(&sB[row * 64 + kt * 32 + l4 * 8]);
      }
#pragma unroll
      for (int m = 0; m < 4; m++)
#pragma unroll
        for (int n = 0; n < 4; n++)
          acc[m][n] = __builtin_amdgcn_mfma_f32_16x16x32_bf16(af[m], bfr[n], acc[m][n], 0, 0, 0);
    }
    __syncthreads();
  }

  const int r0 = bm * 128 + (w >> 1) * 64;
  const int c0 = bn * 128 + (w & 1) * 64;
#pragma unroll
  for (int n = 0; n < 4; n++) {
    int c = c0 + n * 16 + l15;
    float b = bias[c];
#pragma unroll
    for (int m = 0; m < 4; m++)
#pragma unroll
      for (int j = 0; j < 4; j++) {
        int r = r0 + m * 16 + l4 * 4 + j;
        float v = acc[m][n][j] + b;
        if (RELU) v = fmaxf(v, 0.f);
        C[(size_t)r * N + c] = f2bf(v);
      }
  }
}

// ---------- persistent GRU scan: agent/LLC protocol, minimal signal traffic ----------
// 128 WGs = 8 seq-groups(32 seqs) x 16 col-WGs(32 cols); 256 threads = 4 waves.
// Wave (mm,e): rows mm*16..+16, cols e*16..+16, all 3 gates, full K=512.
// PUBLISH: each wave {exchange stores -> s_waitcnt vmcnt(0) -> LDS token (intra-CU)};
//   wave0 min-reduces the 4 tokens, then ONE plain per-WG flag store (agent relaxed).
//   Ordering airtight: h-stores ACKed at LLC before token; flag after all tokens.
// DETECT: wave0 polls the group's 16-flag 64B line (first probe sleep-free, then
//   s_sleep(2)); releases waves 1-3 via an LDS 'go' word. No __syncthreads in loop.
// PIPELINE: gi(t+1) issued during step t (HBM latency off the serial chain);
//   hout stores after the flag publish.
#define GRU_LDS_BYTES (96 * 1024 + 64)

__global__ __launch_bounds__(256, 1)
void gru_scan(const unsigned short* __restrict__ whh,
              const float* __restrict__ b_hh,
              const unsigned short* __restrict__ gi,
              const float* __restrict__ h0f,
              unsigned short* __restrict__ hbA,   // parity 0 writes
              unsigned short* __restrict__ hbB,   // parity 1 writes (pre-filled f2bf(h0))
              float* __restrict__ hout,
              u32* __restrict__ flags) {          // [8 sg][32] u32 (16 used), zeroed
  extern __shared__ char lds[];
  unsigned short* sW = (unsigned short*)lds;      // [96][512] bf16, swizzled
  u32* sCtl = (u32*)(lds + 96 * 1024);            // [0..3]=wave tokens, [8]=go

  const int tid = threadIdx.x;
  const int w = tid >> 6, lane = tid & 63, l15 = lane & 15, l4 = lane >> 4;
  const int sg = blockIdx.x >> 4, cg = blockIdx.x & 15;
  const int s0 = sg * 32;
  const int c0 = cg * 32;
  const int mm = w >> 1, e = w & 1;

  // ---- one-time: stage whh slice rows (gate*512 + c0 + 0..31) ----
  for (int it = 0; it < 24; ++it) {
    int slot = it * 256 + tid;                 // 6144 slots of 16B
    int lcr = slot >> 6, c16 = slot & 63;      // lcr 0..95
    int grow = (lcr >> 5) * 512 + c0 + (lcr & 31);
    ushort8 v = *(const ushort8*)(whh + (size_t)grow * 512 + c16 * 8);
    unsigned byte = ((unsigned)(lcr * 1024 + c16 * 16)) ^ ((unsigned)(lcr & 7) << 4);
    *(ushort8*)((char*)sW + byte) = v;
  }
  if (tid <= 8) sCtl[tid] = 0;                 // tokens + go

  // ---- per-thread constants ----
  const int c = c0 + e * 16 + l15;             // output col
  int rj[4];
#pragma unroll
  for (int j = 0; j < 4; ++j) rj[j] = s0 + mm * 16 + l4 * 4 + j;
  float bias0 = b_hh[c], bias1 = b_hh[512 + c], bias2 = b_hh[1024 + c];
  float hp[4];
#pragma unroll
  for (int j = 0; j < 4; ++j) hp[j] = h0f[(size_t)rj[j] * HH + c];
  size_t houtb[4], gib[4];
#pragma unroll
  for (int j = 0; j < 4; ++j) {
    houtb[j] = (size_t)rj[j] * TT * HH + c;
    gib[j]   = (size_t)rj[j] * TT * G3 + c;
  }
  const int arow = s0 + mm * 16 + l15;         // A-fragment row for this lane
  const unsigned storej = (l15 & 1);           // even lanes store j=0,1; odd j=2,3

  u32* myflag = flags + sg * 32 + cg;          // per-WG flag (16/group in one 64B line)
  const u32* pollp = flags + sg * 32 + l15;

  // ---- prologue: gi(0) loads (complete during staging) ----
  u32 gnext[12];
#pragma unroll
  for (int j = 0; j < 4; ++j) {
    const unsigned short* gp = gi + gib[j];
    gnext[j * 3 + 0] = gp[0];
    gnext[j * 3 + 1] = gp[512];
    gnext[j * 3 + 2] = gp[1024];
  }

  __syncthreads();  // sW + sCtl ready (only barrier in the kernel)

#pragma unroll 1
  for (int t = 0; t < TT; ++t) {
    const unsigned short* rb = (t & 1) ? hbA : hbB;
    unsigned short* wb = (t & 1) ? hbB : hbA;

    if (t > 0) {
      if (w == 0) {
        // poll the 16-flag 64B line: first probe sleep-free, then backoff
        for (;;) {
          u32 v = __hip_atomic_load(pollp, __ATOMIC_RELAXED, __HIP_MEMORY_SCOPE_AGENT);
          int mv = (int)v;
#pragma unroll
          for (int msk = 1; msk <= 8; msk <<= 1) {
            int o = __shfl_xor(mv, msk);
            mv = mv < o ? mv : o;
          }
          if (mv >= t) break;
          __builtin_amdgcn_s_sleep(2);
        }
        __hip_atomic_store(&sCtl[8], (u32)t, __ATOMIC_RELAXED, __HIP_MEMORY_SCOPE_WORKGROUP);
      } else {
        while (__hip_atomic_load(&sCtl[8], __ATOMIC_RELAXED, __HIP_MEMORY_SCOPE_WORKGROUP) < (u32)t) {}
      }
      __builtin_amdgcn_sched_barrier(0);
    }

    // ---- A-fragments first (critical path): 32 relaxed u64 agent loads ----
    const unsigned short* ap = rb + (size_t)arow * HH + l4 * 8;
    u64 av[32];
#pragma unroll
    for (int ktg = 0; ktg < 16; ++ktg) {
      av[2 * ktg]     = __hip_atomic_load((const u64*)(ap + ktg * 32),
                                          __ATOMIC_RELAXED, __HIP_MEMORY_SCOPE_AGENT);
      av[2 * ktg + 1] = __hip_atomic_load((const u64*)(ap + ktg * 32 + 4),
                                          __ATOMIC_RELAXED, __HIP_MEMORY_SCOPE_AGENT);
    }

    // ---- convert gi(t) (loaded last iteration; long complete) ----
    float gv0[4], gv1[4], gv2[4];
#pragma unroll
    for (int j = 0; j < 4; ++j) {
      gv0[j] = bf2f((unsigned short)gnext[j * 3 + 0]);
      gv1[j] = bf2f((unsigned short)gnext[j * 3 + 1]);
      gv2[j] = bf2f((unsigned short)gnext[j * 3 + 2]);
    }

    // ---- issue gi(t+1): HBM latency hides under MFMA+epilogue+publish ----
    {
      int tn = (t + 1 < TT) ? t + 1 : t;
#pragma unroll
      for (int j = 0; j < 4; ++j) {
        const unsigned short* gp = gi + gib[j] + (size_t)tn * G3;
        gnext[j * 3 + 0] = gp[0];
        gnext[j * 3 + 1] = gp[512];
        gnext[j * 3 + 2] = gp[1024];
      }
    }

    // ---- MFMA: 16 k-steps x 3 gates, full K ----
    f32x4 acc[3];
    const f32x4 fz = {0.f, 0.f, 0.f, 0.f};
    acc[0] = fz; acc[1] = fz; acc[2] = fz;
#pragma unroll
    for (int ktg = 0; ktg < 16; ++ktg) {
      union { u64 q[2]; bf16x8 v; } ua;
      ua.q[0] = av[2 * ktg]; ua.q[1] = av[2 * ktg + 1];
      bf16x8 a = ua.v;
#pragma unroll
      for (int g = 0; g < 3; ++g) {
        int lcr = g * 32 + e * 16 + l15;
        unsigned byte = ((unsigned)(lcr * 1024 + ktg * 64 + l4 * 16)) ^ ((unsigned)(lcr & 7) << 4);
        bf16x8 b = ld_bf8_b((const char*)sW, byte);
        acc[g] = __builtin_amdgcn_mfma_f32_16x16x32_bf16(a, b, acc[g], 0, 0, 0);
      }
    }

    // ---- epilogue ----
    float hn[4];
#pragma unroll
    for (int j = 0; j < 4; ++j) {
      float gh0 = acc[0][j] + bias0;
      float gh1 = acc[1][j] + bias1;
      float gh2 = acc[2][j] + bias2;
      float rr = 1.f / (1.f + __expf(-(gv0[j] + gh0)));
      float zz = 1.f / (1.f + __expf(-(gv1[j] + gh1)));
      float nx = gv2[j] + rr * gh2;
      float ex = __expf(2.f * nx);
      float nn = 1.f - 2.f / (ex + 1.f);       // tanh, inf-safe
      hn[j] = (1.f - zz) * nn + zz * hp[j];
      hp[j] = hn[j];
    }

    // ---- exchange: pack col-pairs, relaxed u32 agent stores ----
#pragma unroll
    for (int j = 0; j < 4; ++j) {
      u32 my = f2bf(hn[j]);
      u32 oth = (u32)__shfl_xor((int)my, 1);
      u32 word = (l15 & 1) ? ((oth & 0xffffu) | (my << 16))
                           : ((my & 0xffffu) | (oth << 16));
      if ((unsigned)(j >> 1) == storej) {
        u32* dst = (u32*)(wb + (size_t)rj[j] * HH + (c & ~1));
        __hip_atomic_store(dst, word, __ATOMIC_RELAXED, __HIP_MEMORY_SCOPE_AGENT);
      }
    }

    // ---- publish: per-wave drain -> LDS token; wave0 gathers -> ONE WG flag ----
    asm volatile("s_waitcnt vmcnt(0)" ::: "memory");
    __hip_atomic_store(&sCtl[w], (u32)(t + 1), __ATOMIC_RELAXED, __HIP_MEMORY_SCOPE_WORKGROUP);
    if (w == 0) {
      u32 mt;
      do {
        u32 tv = __hip_atomic_load(&sCtl[lane & 3], __ATOMIC_RELAXED, __HIP_MEMORY_SCOPE_WORKGROUP);
        mt = tv;
#pragma unroll
        for (int msk = 1; msk <= 2; msk <<= 1) {
          u32 o = (u32)__shfl_xor((int)mt, msk);
          mt = mt < o ? mt : o;
        }
      } while (mt < (u32)(t + 1));
      if (lane == 0)
        __hip_atomic_store(myflag, (u32)(t + 1), __ATOMIC_RELAXED, __HIP_MEMORY_SCOPE_AGENT);
    }

    // ---- hout AFTER the publish (drains during the next poll window) ----
#pragma unroll
    for (int j = 0; j < 4; ++j)
      hout[houtb[j] + (size_t)t * HH] = hn[j];
  }
}

// ---------- decoder + softmax ----------
__global__ __launch_bounds__(256)
void decoder_softmax(const float* __restrict__ hf,
                     const unsigned short* __restrict__ dwb,
                     const float* __restrict__ dec_b,
                     float* __restrict__ pi) {
  __shared__ unsigned short sH[64 * 512];
  const int tid = threadIdx.x, w = tid >> 6, lane = tid & 63, l15 = lane & 15, l4 = lane >> 4;
  const size_t m0 = (size_t)blockIdx.x * 64;

#pragma unroll
  for (int it = 0; it < 16; ++it) {
    int slot = it * 256 + tid;
    int row = slot >> 6, c16 = slot & 63;
    const float* g = hf + (m0 + row) * 512 + c16 * 8;
    float4v v0 = *(const float4v*)g;
    float4v v1 = *(const float4v*)(g + 4);
    ushort8 u;
    u[0] = f2bf(v0[0]); u[1] = f2bf(v0[1]); u[2] = f2bf(v0[2]); u[3] = f2bf(v0[3]);
    u[4] = f2bf(v1[0]); u[5] = f2bf(v1[1]); u[6] = f2bf(v1[2]); u[7] = f2bf(v1[3]);
    unsigned byte = ((unsigned)(row * 1024 + c16 * 16)) ^ ((unsigned)(row & 7) << 4);
    *(ushort8*)((char*)sH + byte) = u;
  }
  __syncthreads();

  f32x4 acc[4];
  const f32x4 fz = {0.f, 0.f, 0.f, 0.f};
#pragma unroll
  for (int n = 0; n < 4; n++) acc[n] = fz;

  for (int kt = 0; kt < 16; ++kt) {
    int row = w * 16 + l15;
    unsigned byte = ((unsigned)(row * 1024 + kt * 64 + l4 * 16)) ^ ((unsigned)(row & 7) << 4);
    bf16x8 a = ld_bf8_b((const char*)sH, byte);
#pragma unroll
    for (int nt = 0; nt < 4; nt++) {
      bf16x8 b = ld_bf8_g(dwb + (size_t)(nt * 16 + l15) * 512 + kt * 32 + l4 * 8);
      acc[nt] = __builtin_amdgcn_mfma_f32_16x16x32_bf16(a, b, acc[nt], 0, 0, 0);
    }
  }

#pragma unroll
  for (int j = 0; j < 4; j++) {
    size_t r = m0 + w * 16 + l4 * 4 + j;
    float v[4];
    float mx = -1e30f;
#pragma unroll
    for (int nt = 0; nt < 4; nt++) {
      v[nt] = fmaxf(acc[nt][j] + dec_b[nt * 16 + l15], 0.f);
      mx = fmaxf(mx, v[nt]);
    }
#pragma unroll
    for (int msk = 1; msk <= 8; msk <<= 1) mx = fmaxf(mx, __shfl_xor(mx, msk));
    float s = 0.f;
#pragma unroll
    for (int nt = 0; nt < 4; nt++) { v[nt] = __expf(v[nt] - mx); s += v[nt]; }
#pragma unroll
    for (int msk = 1; msk <= 8; msk <<= 1) s += __shfl_xor(s, msk);
    float inv = 1.f / s;
#pragma unroll
    for (int nt = 0; nt < 4; nt++) pi[r * 64 + nt * 16 + l15] = v[nt] * inv;
  }
}

extern "C" void kernel_launch(void* const* d_in, const int* in_sizes, int n_in,
                              void* d_out, int out_size, void* d_ws, size_t ws_size,
                              hipStream_t stream) {
  const float* x     = (const float*)d_in[0];
  const float* h0    = (const float*)d_in[1];
  const float* enc_w = (const float*)d_in[2];
  const float* enc_b = (const float*)d_in[3];
  const float* w_ih  = (const float*)d_in[4];
  const float* w_hh  = (const float*)d_in[5];
  const float* b_ih  = (const float*)d_in[6];
  const float* b_hh  = (const float*)d_in[7];
  const float* dec_w = (const float*)d_in[8];
  const float* dec_b = (const float*)d_in[9];

  float* pi_out = (float*)d_out;
  float* h_out  = (float*)d_out + 4194304;

  unsigned short* ws = (unsigned short*)d_ws;
  size_t off = 0;
  unsigned short* x_bf    = ws + off; off += (size_t)MROWS * VV;
  unsigned short* enc_bf  = ws + off; off += (size_t)MROWS * EE;
  unsigned short* gi_bf   = ws + off; off += (size_t)MROWS * G3;
  unsigned short* encw_bf = ws + off; off += (size_t)EE * VV;
  unsigned short* wih_bf  = ws + off; off += (size_t)G3 * EE;
  unsigned short* whh_bf  = ws + off; off += (size_t)G3 * HH;
  unsigned short* decw_bf = ws + off; off += (size_t)NA * HH;
  unsigned short* hb0     = ws + off; off += (size_t)NSEQ * HH;
  unsigned short* hb1     = ws + off; off += (size_t)NSEQ * HH;
  u32* flags = (u32*)((((uintptr_t)(ws + off)) + 255) & ~(uintptr_t)255);
  (void)ws_size; (void)in_sizes; (void)n_in; (void)out_size;

  hipFuncSetAttribute((const void*)gru_scan,
                      hipFuncAttributeMaxDynamicSharedMemorySize, GRU_LDS_BYTES);

  auto cast = [&](const float* s, unsigned short* d, int n) {
    int blocks = (n + 255) / 256; if (blocks > 2048) blocks = 2048;
    cast_f32_bf16<<<blocks, 256, 0, stream>>>(s, d, n);
  };
  cast(x, x_bf, MROWS * VV);
  cast(enc_w, encw_bf, EE * VV);
  cast(w_ih, wih_bf, G3 * EE);
  cast(w_hh, whh_bf, G3 * HH);
  cast(dec_w, decw_bf, NA * HH);
  cast(h0, hb1, NSEQ * HH);              // t=0 reads hbB == hb1

  zero_u32<<<1, 256, 0, stream>>>(flags, 256);

  gemm_bt<true><<<(MROWS / 128) * (EE / 128), 256, 0, stream>>>(x_bf, encw_bf, enc_b, enc_bf, EE, VV);
  gemm_bt<false><<<(MROWS / 128) * (G3 / 128), 256, 0, stream>>>(enc_bf, wih_bf, b_ih, gi_bf, G3, EE);

  gru_scan<<<dim3(128), dim3(256), GRU_LDS_BYTES, stream>>>(
      whh_bf, b_hh, gi_bf, h0, hb0, hb1, h_out, flags);

  decoder_softmax<<<1024, 256, 0, stream>>>(h_out, decw_bf, dec_b, pi_out);
}

// Round 10
// 1707.319 us; speedup vs baseline: 1.2091x; 1.0715x over previous
//
#include <hip/hip_runtime.h>
#include <hip/hip_bf16.h>

typedef __bf16 bf16x8 __attribute__((ext_vector_type(8)));
typedef float f32x4 __attribute__((ext_vector_type(4)));
typedef unsigned short ushort8 __attribute__((ext_vector_type(8)));
typedef float float4v __attribute__((ext_vector_type(4)));
typedef unsigned int uint4v __attribute__((ext_vector_type(4)));
typedef unsigned long long u64;
typedef unsigned int u32;

#define DEVI __device__ __forceinline__

// ---- sizes (compile-time) ----
#define NSEQ 256      // A_*BS
#define TT 256        // T
#define VV 128        // V
#define EE 512        // E
#define HH 512        // H
#define NA 64
#define MROWS 65536   // NSEQ*T
#define G3 1536       // 3*H

DEVI unsigned short f2bf(float f) {
  union { float f; unsigned u; } v; v.f = f;
  unsigned r = v.u + 0x7fffu + ((v.u >> 16) & 1u);
  return (unsigned short)(r >> 16);
}
DEVI float bf2f(unsigned short s) {
  union { unsigned u; float f; } v; v.u = ((unsigned)s) << 16;
  return v.f;
}
DEVI bf16x8 ld_bf8_g(const unsigned short* p) {
  ushort8 v = *(const ushort8*)p;
  return __builtin_bit_cast(bf16x8, v);
}
DEVI bf16x8 ld_bf8_b(const char* base, unsigned byte) {
  ushort8 v = *(const ushort8*)(base + byte);
  return __builtin_bit_cast(bf16x8, v);
}
DEVI void gload_lds16(const void* g, unsigned short* lds_base, unsigned lds_byte_off) {
  __builtin_amdgcn_global_load_lds(
      (const __attribute__((address_space(1))) unsigned int*)g,
      (__attribute__((address_space(3))) unsigned int*)(void*)((char*)lds_base + lds_byte_off),
      16, 0, 0);
}
// LLC-coherent 16B load (bypass L1+L2): issue only, caller does the waitcnt.
DEVI void ld_chunk_sc(uint4v* dst, const void* p) {
  asm volatile("global_load_dwordx4 %0, %1, off sc0 sc1"
               : "=&v"(*dst) : "v"((u64)p) : "memory");
}

// ---------- cast fp32 -> bf16(raw u16) ----------
__global__ void cast_f32_bf16(const float* __restrict__ src, unsigned short* __restrict__ dst, int n) {
  int i = blockIdx.x * blockDim.x + threadIdx.x;
  int stride = gridDim.x * blockDim.x;
  for (; i < n; i += stride) dst[i] = f2bf(src[i]);
}

__global__ void zero_u32(u32* __restrict__ p, int n) {
  int i = blockIdx.x * blockDim.x + threadIdx.x;
  if (i < n) p[i] = 0u;
}

// ---------- GEMM: C_bf[M,N] = act(A_bf[M,K] @ W_bf[N,K]^T + bias[N]) ----------
template<bool RELU>
__global__ __launch_bounds__(256)
void gemm_bt(const unsigned short* __restrict__ A, const unsigned short* __restrict__ W,
             const float* __restrict__ bias, unsigned short* __restrict__ C,
             int N, int K) {
  __shared__ unsigned short sA[128 * 64];
  __shared__ unsigned short sB[128 * 64];
  const int tid = threadIdx.x;
  const int w = tid >> 6, lane = tid & 63;
  const int l15 = lane & 15, l4 = lane >> 4;
  const int nbn = N >> 7;
  const int bm = blockIdx.x / nbn, bn = blockIdx.x % nbn;

  f32x4 acc[4][4];
  const f32x4 fz = {0.f, 0.f, 0.f, 0.f};
#pragma unroll
  for (int i = 0; i < 4; i++)
#pragma unroll
    for (int j = 0; j < 4; j++) acc[i][j] = fz;

  const int nk = K >> 6;
  for (int bk = 0; bk < nk; ++bk) {
#pragma unroll
    for (int it = 0; it < 4; ++it) {
      int slot = it * 256 + tid;
      int row = slot >> 3, c16 = slot & 7;
      const unsigned short* ga = A + (size_t)(bm * 128 + row) * K + bk * 64 + c16 * 8;
      const unsigned short* gb = W + (size_t)(bn * 128 + row) * K + bk * 64 + c16 * 8;
      unsigned ldsoff = (unsigned)(it * 256 + w * 64) * 16;
      gload_lds16(ga, sA, ldsoff);
      gload_lds16(gb, sB, ldsoff);
    }
    __syncthreads();
#pragma unroll
    for (int kt = 0; kt < 2; ++kt) {
      bf16x8 af[4], bfr[4];
#pragma unroll
      for (int m = 0; m < 4; m++) {
        int row = ((w >> 1) * 64) + m * 16 + l15;
        af[m] = ld_bf8_g(&sA[row * 64 + kt * 32 + l4 * 8]);
      }
#pragma unroll
      for (int n = 0; n < 4; n++) {
        int row = ((w & 1) * 64) + n * 16 + l15;
        bfr[n] = ld_bf8_g(&sB[row * 64 + kt * 32 + l4 * 8]);
      }
#pragma unroll
      for (int m = 0; m < 4; m++)
#pragma unroll
        for (int n = 0; n < 4; n++)
          acc[m][n] = __builtin_amdgcn_mfma_f32_16x16x32_bf16(af[m], bfr[n], acc[m][n], 0, 0, 0);
    }
    __syncthreads();
  }

  const int r0 = bm * 128 + (w >> 1) * 64;
  const int c0 = bn * 128 + (w & 1) * 64;
#pragma unroll
  for (int n = 0; n < 4; n++) {
    int c = c0 + n * 16 + l15;
    float b = bias[c];
#pragma unroll
    for (int m = 0; m < 4; m++)
#pragma unroll
      for (int j = 0; j < 4; j++) {
        int r = r0 + m * 16 + l4 * 4 + j;
        float v = acc[m][n][j] + b;
        if (RELU) v = fmaxf(v, 0.f);
        C[(size_t)r * N + c] = f2bf(v);
      }
  }
}

// ---------- persistent GRU scan: mask-prefix chunked acquire ----------
// 128 WGs = 8 seq-groups(32 seqs) x 16 col-WGs(32 cols); 256 threads = 4 waves.
// Wave (mm,e): rows mm*16..+16, cols e*16..+16, all 3 gates, full K=512.
// ACQUIRE: A-chunk ktg depends ONLY on producer WG cg'=ktg. Each wave polls the
//   16-WG-flag 64B line (ballot -> ready mask) and issues chunk loads in rotated
//   order as producers become ready — load pull & straggler wait overlap.
// PUBLISH (R8-proven): per wave {exchange -> vmcnt(0) -> LDS token}; wave0 gathers
//   tokens -> ONE per-WG flag store. No RMW, no __syncthreads in loop.
// hout: LDS ring (8 steps), flushed after publish every 8 steps — keeps scattered
//   HBM store ACKs out of the per-step vmcnt(0) drains.
#define GRU_LDS_BYTES (96 * 1024 + 32 * 1024 + 64)

__global__ __launch_bounds__(256, 1)
void gru_scan(const unsigned short* __restrict__ whh,
              const float* __restrict__ b_hh,
              const unsigned short* __restrict__ gi,
              const float* __restrict__ h0f,
              unsigned short* __restrict__ hbA,   // parity 0 writes
              unsigned short* __restrict__ hbB,   // parity 1 writes (pre-filled f2bf(h0))
              float* __restrict__ hout,
              u32* __restrict__ flags) {          // [8 sg][32] u32 (16 used), zeroed
  extern __shared__ char lds[];
  unsigned short* sW = (unsigned short*)lds;       // [96][512] bf16, swizzled
  float* sRing = (float*)(lds + 96 * 1024);        // [8][256 tid][4] f32
  u32* sCtl = (u32*)(lds + 128 * 1024);            // [0..3] wave tokens

  const int tid = threadIdx.x;
  const int w = tid >> 6, lane = tid & 63, l15 = lane & 15, l4 = lane >> 4;
  const int sg = blockIdx.x >> 4, cg = blockIdx.x & 15;
  const int s0 = sg * 32;
  const int c0 = cg * 32;
  const int mm = w >> 1, e = w & 1;

  // ---- one-time: stage whh slice rows (gate*512 + c0 + 0..31) ----
  for (int it = 0; it < 24; ++it) {
    int slot = it * 256 + tid;                 // 6144 slots of 16B
    int lcr = slot >> 6, c16 = slot & 63;      // lcr 0..95
    int grow = (lcr >> 5) * 512 + c0 + (lcr & 31);
    ushort8 v = *(const ushort8*)(whh + (size_t)grow * 512 + c16 * 8);
    unsigned byte = ((unsigned)(lcr * 1024 + c16 * 16)) ^ ((unsigned)(lcr & 7) << 4);
    *(ushort8*)((char*)sW + byte) = v;
  }
  if (tid < 4) sCtl[tid] = 0;

  // ---- per-thread constants ----
  const int c = c0 + e * 16 + l15;             // output col
  int rj[4];
#pragma unroll
  for (int j = 0; j < 4; ++j) rj[j] = s0 + mm * 16 + l4 * 4 + j;
  float bias0 = b_hh[c], bias1 = b_hh[512 + c], bias2 = b_hh[1024 + c];
  float hp[4];
#pragma unroll
  for (int j = 0; j < 4; ++j) hp[j] = h0f[(size_t)rj[j] * HH + c];
  size_t houtb[4], gib[4];
#pragma unroll
  for (int j = 0; j < 4; ++j) {
    houtb[j] = (size_t)rj[j] * TT * HH + c;
    gib[j]   = (size_t)rj[j] * TT * G3 + c;
  }
  const int arow = s0 + mm * 16 + l15;         // A-fragment row for this lane
  const unsigned storej = (l15 & 1);           // even lanes store j=0,1; odd j=2,3

  u32* myflag = flags + sg * 32 + cg;          // per-WG flag
  const u32* pollp = flags + sg * 32 + l15;    // 16-flag 64B line, lane-indexed

  // ---- prologue: gi(0) loads (retire during staging) ----
  unsigned short gnext[12];
#pragma unroll
  for (int j = 0; j < 4; ++j) {
    const unsigned short* gp = gi + gib[j];
    gnext[j * 3 + 0] = gp[0];
    gnext[j * 3 + 1] = gp[512];
    gnext[j * 3 + 2] = gp[1024];
  }

  __syncthreads();  // sW + sCtl ready (only barrier in the kernel)

#pragma unroll 1
  for (int t = 0; t < TT; ++t) {
    const unsigned short* rb = (t & 1) ? hbA : hbB;
    unsigned short* wb = (t & 1) ? hbB : hbA;

    // convert gi(t) (loaded during previous step's MFMA phase; long retired)
    float gv0[4], gv1[4], gv2[4];
#pragma unroll
    for (int j = 0; j < 4; ++j) {
      gv0[j] = bf2f(gnext[j * 3 + 0]);
      gv1[j] = bf2f(gnext[j * 3 + 1]);
      gv2[j] = bf2f(gnext[j * 3 + 2]);
    }

    // ---- ACQUIRE: poll ready-mask, issue chunk loads in rotated order ----
    const char* abase = (const char*)(rb + (size_t)arow * HH) + l4 * 16;
    uint4v av4[16];
    u32 mask;
    {
      u32 fv = __hip_atomic_load(pollp, __ATOMIC_RELAXED, __HIP_MEMORY_SCOPE_AGENT);
      u64 bal = __ballot(fv >= (u32)t);
      mask = (u32)(bal & 0xffffu);
    }
#pragma unroll
    for (int i = 0; i < 16; ++i) {
      int ktg = (cg + i) & 15;
      while (!((mask >> ktg) & 1u)) {
        __builtin_amdgcn_s_sleep(1);
        u32 fv = __hip_atomic_load(pollp, __ATOMIC_RELAXED, __HIP_MEMORY_SCOPE_AGENT);
        u64 bal = __ballot(fv >= (u32)t);
        mask = (u32)(bal & 0xffffu);
      }
      ld_chunk_sc(&av4[i], abase + (size_t)ktg * 64);
    }
    asm volatile("s_waitcnt vmcnt(0)" ::: "memory");
    __builtin_amdgcn_sched_barrier(0);

    // ---- issue gi(t+1): retires under the MFMA phase ----
    {
      int tn = (t + 1 < TT) ? t + 1 : t;
#pragma unroll
      for (int j = 0; j < 4; ++j) {
        const unsigned short* gp = gi + gib[j] + (size_t)tn * G3;
        gnext[j * 3 + 0] = gp[0];
        gnext[j * 3 + 1] = gp[512];
        gnext[j * 3 + 2] = gp[1024];
      }
    }

    // ---- MFMA: 16 chunks x 3 gates ----
    f32x4 acc[3];
    const f32x4 fz = {0.f, 0.f, 0.f, 0.f};
    acc[0] = fz; acc[1] = fz; acc[2] = fz;
#pragma unroll
    for (int i = 0; i < 16; ++i) {
      int ktg = (cg + i) & 15;
      bf16x8 a = __builtin_bit_cast(bf16x8, av4[i]);
#pragma unroll
      for (int g = 0; g < 3; ++g) {
        int lcr = g * 32 + e * 16 + l15;
        unsigned byte = ((unsigned)(lcr * 1024 + ktg * 64 + l4 * 16)) ^ ((unsigned)(lcr & 7) << 4);
        bf16x8 b = ld_bf8_b((const char*)sW, byte);
        acc[g] = __builtin_amdgcn_mfma_f32_16x16x32_bf16(a, b, acc[g], 0, 0, 0);
      }
    }

    // ---- epilogue ----
    float hn[4];
#pragma unroll
    for (int j = 0; j < 4; ++j) {
      float gh0 = acc[0][j] + bias0;
      float gh1 = acc[1][j] + bias1;
      float gh2 = acc[2][j] + bias2;
      float rr = 1.f / (1.f + __expf(-(gv0[j] + gh0)));
      float zz = 1.f / (1.f + __expf(-(gv1[j] + gh1)));
      float nx = gv2[j] + rr * gh2;
      float ex = __expf(2.f * nx);
      float nn = 1.f - 2.f / (ex + 1.f);       // tanh, inf-safe
      hn[j] = (1.f - zz) * nn + zz * hp[j];
      hp[j] = hn[j];
    }

    // ---- exchange: pack col-pairs, relaxed u32 agent stores ----
#pragma unroll
    for (int j = 0; j < 4; ++j) {
      u32 my = f2bf(hn[j]);
      u32 oth = (u32)__shfl_xor((int)my, 1);
      u32 word = (l15 & 1) ? ((oth & 0xffffu) | (my << 16))
                           : ((my & 0xffffu) | (oth << 16));
      if ((unsigned)(j >> 1) == storej) {
        u32* dst = (u32*)(wb + (size_t)rj[j] * HH + (c & ~1));
        __hip_atomic_store(dst, word, __ATOMIC_RELAXED, __HIP_MEMORY_SCOPE_AGENT);
      }
    }

    // ---- publish: per-wave drain -> LDS token; wave0 gathers -> ONE WG flag ----
    asm volatile("s_waitcnt vmcnt(0)" ::: "memory");
    __hip_atomic_store(&sCtl[w], (u32)(t + 1), __ATOMIC_RELAXED, __HIP_MEMORY_SCOPE_WORKGROUP);
    if (w == 0) {
      u32 mt;
      do {
        u32 tv = __hip_atomic_load(&sCtl[lane & 3], __ATOMIC_RELAXED, __HIP_MEMORY_SCOPE_WORKGROUP);
        mt = tv;
#pragma unroll
        for (int msk = 1; msk <= 2; msk <<= 1) {
          u32 o = (u32)__shfl_xor((int)mt, msk);
          mt = mt < o ? mt : o;
        }
      } while (mt < (u32)(t + 1));
      if (lane == 0)
        __hip_atomic_store(myflag, (u32)(t + 1), __ATOMIC_RELAXED, __HIP_MEMORY_SCOPE_AGENT);
    }

    // ---- hout -> LDS ring; bulk flush every 8 steps (off the serial chain) ----
    {
      float* slot = sRing + (((t & 7) * 256 + tid) << 2);
#pragma unroll
      for (int j = 0; j < 4; ++j) slot[j] = hn[j];
    }
    if ((t & 7) == 7) {
      int tb = t - 7;
#pragma unroll
      for (int tt = 0; tt < 8; ++tt) {
        const float* src = sRing + ((tt * 256 + tid) << 2);
#pragma unroll
        for (int j = 0; j < 4; ++j)
          hout[houtb[j] + (size_t)(tb + tt) * HH] = src[j];
      }
    }
  }
}

// ---------- decoder + softmax ----------
__global__ __launch_bounds__(256)
void decoder_softmax(const float* __restrict__ hf,
                     const unsigned short* __restrict__ dwb,
                     const float* __restrict__ dec_b,
                     float* __restrict__ pi) {
  __shared__ unsigned short sH[64 * 512];
  const int tid = threadIdx.x, w = tid >> 6, lane = tid & 63, l15 = lane & 15, l4 = lane >> 4;
  const size_t m0 = (size_t)blockIdx.x * 64;

#pragma unroll
  for (int it = 0; it < 16; ++it) {
    int slot = it * 256 + tid;
    int row = slot >> 6, c16 = slot & 63;
    const float* g = hf + (m0 + row) * 512 + c16 * 8;
    float4v v0 = *(const float4v*)g;
    float4v v1 = *(const float4v*)(g + 4);
    ushort8 u;
    u[0] = f2bf(v0[0]); u[1] = f2bf(v0[1]); u[2] = f2bf(v0[2]); u[3] = f2bf(v0[3]);
    u[4] = f2bf(v1[0]); u[5] = f2bf(v1[1]); u[6] = f2bf(v1[2]); u[7] = f2bf(v1[3]);
    unsigned byte = ((unsigned)(row * 1024 + c16 * 16)) ^ ((unsigned)(row & 7) << 4);
    *(ushort8*)((char*)sH + byte) = u;
  }
  __syncthreads();

  f32x4 acc[4];
  const f32x4 fz = {0.f, 0.f, 0.f, 0.f};
#pragma unroll
  for (int n = 0; n < 4; n++) acc[n] = fz;

  for (int kt = 0; kt < 16; ++kt) {
    int row = w * 16 + l15;
    unsigned byte = ((unsigned)(row * 1024 + kt * 64 + l4 * 16)) ^ ((unsigned)(row & 7) << 4);
    bf16x8 a = ld_bf8_b((const char*)sH, byte);
#pragma unroll
    for (int nt = 0; nt < 4; nt++) {
      bf16x8 b = ld_bf8_g(dwb + (size_t)(nt * 16 + l15) * 512 + kt * 32 + l4 * 8);
      acc[nt] = __builtin_amdgcn_mfma_f32_16x16x32_bf16(a, b, acc[nt], 0, 0, 0);
    }
  }

#pragma unroll
  for (int j = 0; j < 4; j++) {
    size_t r = m0 + w * 16 + l4 * 4 + j;
    float v[4];
    float mx = -1e30f;
#pragma unroll
    for (int nt = 0; nt < 4; nt++) {
      v[nt] = fmaxf(acc[nt][j] + dec_b[nt * 16 + l15], 0.f);
      mx = fmaxf(mx, v[nt]);
    }
#pragma unroll
    for (int msk = 1; msk <= 8; msk <<= 1) mx = fmaxf(mx, __shfl_xor(mx, msk));
    float s = 0.f;
#pragma unroll
    for (int nt = 0; nt < 4; nt++) { v[nt] = __expf(v[nt] - mx); s += v[nt]; }
#pragma unroll
    for (int msk = 1; msk <= 8; msk <<= 1) s += __shfl_xor(s, msk);
    float inv = 1.f / s;
#pragma unroll
    for (int nt = 0; nt < 4; nt++) pi[r * 64 + nt * 16 + l15] = v[nt] * inv;
  }
}

extern "C" void kernel_launch(void* const* d_in, const int* in_sizes, int n_in,
                              void* d_out, int out_size, void* d_ws, size_t ws_size,
                              hipStream_t stream) {
  const float* x     = (const float*)d_in[0];
  const float* h0    = (const float*)d_in[1];
  const float* enc_w = (const float*)d_in[2];
  const float* enc_b = (const float*)d_in[3];
  const float* w_ih  = (const float*)d_in[4];
  const float* w_hh  = (const float*)d_in[5];
  const float* b_ih  = (const float*)d_in[6];
  const float* b_hh  = (const float*)d_in[7];
  const float* dec_w = (const float*)d_in[8];
  const float* dec_b = (const float*)d_in[9];

  float* pi_out = (float*)d_out;
  float* h_out  = (float*)d_out + 4194304;

  unsigned short* ws = (unsigned short*)d_ws;
  size_t off = 0;
  unsigned short* x_bf    = ws + off; off += (size_t)MROWS * VV;
  unsigned short* enc_bf  = ws + off; off += (size_t)MROWS * EE;
  unsigned short* gi_bf   = ws + off; off += (size_t)MROWS * G3;
  unsigned short* encw_bf = ws + off; off += (size_t)EE * VV;
  unsigned short* wih_bf  = ws + off; off += (size_t)G3 * EE;
  unsigned short* whh_bf  = ws + off; off += (size_t)G3 * HH;
  unsigned short* decw_bf = ws + off; off += (size_t)NA * HH;
  unsigned short* hb0     = ws + off; off += (size_t)NSEQ * HH;
  unsigned short* hb1     = ws + off; off += (size_t)NSEQ * HH;
  u32* flags = (u32*)((((uintptr_t)(ws + off)) + 255) & ~(uintptr_t)255);
  (void)ws_size; (void)in_sizes; (void)n_in; (void)out_size;

  hipFuncSetAttribute((const void*)gru_scan,
                      hipFuncAttributeMaxDynamicSharedMemorySize, GRU_LDS_BYTES);

  auto cast = [&](const float* s, unsigned short* d, int n) {
    int blocks = (n + 255) / 256; if (blocks > 2048) blocks = 2048;
    cast_f32_bf16<<<blocks, 256, 0, stream>>>(s, d, n);
  };
  cast(x, x_bf, MROWS * VV);
  cast(enc_w, encw_bf, EE * VV);
  cast(w_ih, wih_bf, G3 * EE);
  cast(w_hh, whh_bf, G3 * HH);
  cast(dec_w, decw_bf, NA * HH);
  cast(h0, hb1, NSEQ * HH);              // t=0 reads hbB == hb1

  zero_u32<<<1, 256, 0, stream>>>(flags, 256);

  gemm_bt<true><<<(MROWS / 128) * (EE / 128), 256, 0, stream>>>(x_bf, encw_bf, enc_b, enc_bf, EE, VV);
  gemm_bt<false><<<(MROWS / 128) * (G3 / 128), 256, 0, stream>>>(enc_bf, wih_bf, b_ih, gi_bf, G3, EE);

  gru_scan<<<dim3(128), dim3(256), GRU_LDS_BYTES, stream>>>(
      whh_bf, b_hh, gi_bf, h0, hb0, hb1, h_out, flags);

  decoder_softmax<<<1024, 256, 0, stream>>>(h_out, decw_bf, dec_b, pi_out);
}